// Round 20
// baseline (39.267 us; speedup 1.0000x reference)
//
#include <hip/hip_runtime.h>
#include <math.h>

// B=4, N=16, K=16, H=64, O=1.  W: (a,b,d,e,k,o) fp32 = 256 MiB.
// h[z,a,o] = sum_j P[z,a,j] W[a,j,o];  P = <basis(a,b,k),basis(d,e,k)>_z
// out[z,a] = silu(h[z,a,:]) . w_fc + b_fc
//
// Cosine cutoff (dist>=5) + zero diagonal kill ~73% of W rows exactly ->
// their loads are skipped (bit-exact, ballot-derived wave-uniform mask).
// R20 = R17 body (best, 28.2us) FUSED to ONE kernel:
//  - each block atomicAdds its 256 partial h values as int64 FIXED-POINT
//    (scale 2^28): integer adds are exactly associative -> bitwise
//    deterministic regardless of arrival order. NO FENCES (R16's killer).
//  - per-'a' ticket: the 128th block re-reads the accumulators with
//    atomic RMWs (coherence-point reads; no stale-L2 hazard) and does
//    silu + w_fc dot + out write.
//  - 32 KB hacc + 64 B tickets reset per launch by one hipMemsetAsync.
// Saves: k_out launch + inter-kernel drain (~9us model) + part 4 MB RT.
//
// ws bytes: hacc u64[4096] @ 0 (32768 B), done u32[16] @ 32768.

#define NJ 65536
#define BPA 128   // blocks per 'a' -> 2048 blocks
#define FPSCALE 268435456.0f   // 2^28

typedef float f32x4 __attribute__((ext_vector_type(4)));
typedef unsigned int u32;
typedef unsigned long long u64;

static constexpr double D_START = 0.006737946999085467; // exp(-5)

#define ACC8(pA, pB, wA, wB) do {                                              \
    acc[0][0] += pA.x * wA.x + pB.x * wB.x; acc[0][1] += pA.x * wA.y + pB.x * wB.y; \
    acc[0][2] += pA.x * wA.z + pB.x * wB.z; acc[0][3] += pA.x * wA.w + pB.x * wB.w; \
    acc[1][0] += pA.y * wA.x + pB.y * wB.x; acc[1][1] += pA.y * wA.y + pB.y * wB.y; \
    acc[1][2] += pA.y * wA.z + pB.y * wB.z; acc[1][3] += pA.y * wA.w + pB.y * wB.w; \
    acc[2][0] += pA.z * wA.x + pB.z * wB.x; acc[2][1] += pA.z * wA.y + pB.z * wB.y; \
    acc[2][2] += pA.z * wA.z + pB.z * wB.z; acc[2][3] += pA.z * wA.w + pB.z * wB.w; \
    acc[3][0] += pA.w * wA.x + pB.w * wB.x; acc[3][1] += pA.w * wA.y + pB.w * wB.y; \
    acc[3][2] += pA.w * wA.z + pB.w * wB.z; acc[3][3] += pA.w * wA.w + pB.w * wB.w; \
} while (0)

// basis vector (smear_k * diff / nsq) for pair (p,q) in batch z, rbf k.
__device__ __forceinline__ bool pair_basis(const float* __restrict__ x,
                                           int z, int p, int q, int k,
                                           float& bx, float& by, float& bz) {
    const float* xp = x + (z * 16 + p) * 3;
    const float* xq = x + (z * 16 + q) * 3;
    float d0 = xp[0] - xq[0], d1 = xp[1] - xq[1], d2 = xp[2] - xq[2];
    float nsq = d0 * d0 + d1 * d1 + d2 * d2 + 1e-5f;
    float nrm = sqrtf(nsq);
    if (nrm >= 5.0f) return false;                 // cut == 0 -> basis == 0
    float cut = 0.5f * (cosf(nrm * 0.6283185307179586f) + 1.0f);
    float ex = expf(-nrm); // alpha=1, CUT_LO=0
    const float START = (float)D_START;
    const float STEP  = (float)((1.0 - D_START) / 15.0);
    const float BETA  = (float)(1.0 / ((0.125 * (1.0 - D_START)) * (0.125 * (1.0 - D_START))));
    float m = START + STEP * (float)k;
    float dmm = ex - m;
    float s = cut * expf(-BETA * dmm * dmm) / nsq; // fold /nsq of diff into smear
    bx = s * d0; by = s * d1; bz = s * d2;
    return true;
}

__global__ __launch_bounds__(256) void k_main(const f32x4* __restrict__ W4,
                                              const float* __restrict__ x,
                                              const float* __restrict__ w_fc,
                                              const float* __restrict__ b_fc,
                                              u64* __restrict__ hacc,
                                              u32* __restrict__ done,
                                              float* __restrict__ out) {
    int a   = blockIdx.x >> 7;        // sequential mapping (best measured)
    int blk = blockIdx.x & (BPA - 1); // (b, d-pair)

    __shared__ f32x4 p_lds[512];
    __shared__ float red[4][256];
    __shared__ u32 s_ticket;

    // ---- prologue: P for this block's 512 j-rows (j = blk*512 + rloc) ----
    int t = threadIdx.x;
    f32x4 p0 = {0.f, 0.f, 0.f, 0.f}, p1 = {0.f, 0.f, 0.f, 0.f};
    {
        int e = t >> 4, k = t & 15;
        int b = blk >> 3, dd = (blk & 7) * 2;
        #pragma unroll
        for (int z = 0; z < 4; ++z) {
            float ux, uy, uz;
            if (pair_basis(x, z, a, b, k, ux, uy, uz)) { // block-uniform branch
                float vx, vy, vz;
                if (pair_basis(x, z, dd, e, k, vx, vy, vz))
                    p0[z] = ux * vx + uy * vy + uz * vz;
                if (pair_basis(x, z, dd + 1, e, k, vx, vy, vz))
                    p1[z] = ux * vx + uy * vy + uz * vz;
            }
        }
    }
    bool f0 = (fabsf(p0.x) + fabsf(p0.y) + fabsf(p0.z) + fabsf(p0.w)) != 0.0f;
    bool f1 = (fabsf(p1.x) + fabsf(p1.y) + fabsf(p1.z) + fabsf(p1.w)) != 0.0f;
    unsigned long long bal0 = __ballot(f0);  // rows [w*64, w*64+64)
    unsigned long long bal1 = __ballot(f1);  // rows [256+w*64, ...)
    p_lds[t]       = p0;
    p_lds[t + 256] = p1;
    __syncthreads();

    int wave = t >> 6;
    int lane = t & 63;
    int og   = lane & 15;  // group of 4 'o' columns
    int rsub = lane >> 4;  // row within the 4-row group

    // group mask: bits 0..7 = A-half groups, 8..15 = B-half groups
    unsigned mask = 0;
    #pragma unroll
    for (int g = 0; g < 8; ++g) {
        if ((bal0 >> (8 * g)) & 0xFFull) mask |= 1u << g;
        if ((bal1 >> (8 * g)) & 0xFFull) mask |= 1u << (g + 8);
    }

    float acc[4][4] = {{0.f, 0.f, 0.f, 0.f}, {0.f, 0.f, 0.f, 0.f},
                       {0.f, 0.f, 0.f, 0.f}, {0.f, 0.f, 0.f, 0.f}};
    size_t rowbase = (size_t)a * NJ + (size_t)blk * 512;
    // ---- 2-group-per-iter pipelined skip loop (4 KB in flight) ----
    while (mask) {  // wave-uniform: mask derived from ballots
        int g1 = __builtin_ctz(mask);
        mask &= mask - 1;
        int rloc1 = ((g1 & 8) ? 256 : 0) + wave * 64 + (g1 & 7) * 8 + rsub;
        f32x4 pA1 = p_lds[rloc1];
        f32x4 pB1 = p_lds[rloc1 + 4];
        f32x4 wA1 = W4[(rowbase + rloc1) * 16 + og];
        f32x4 wB1 = W4[(rowbase + rloc1 + 4) * 16 + og];
        if (mask) {
            int g2 = __builtin_ctz(mask);
            mask &= mask - 1;
            int rloc2 = ((g2 & 8) ? 256 : 0) + wave * 64 + (g2 & 7) * 8 + rsub;
            f32x4 pA2 = p_lds[rloc2];
            f32x4 pB2 = p_lds[rloc2 + 4];
            f32x4 wA2 = W4[(rowbase + rloc2) * 16 + og];   // in flight
            f32x4 wB2 = W4[(rowbase + rloc2 + 4) * 16 + og];
            ACC8(pA1, pB1, wA1, wB1);                      // waits vmcnt(2)
            ACC8(pA2, pB2, wA2, wB2);
        } else {
            ACC8(pA1, pB1, wA1, wB1);
        }
    }

    // reduce across the 4 row-subgroups (lane bits 4,5)
    #pragma unroll
    for (int z = 0; z < 4; ++z) {
        #pragma unroll
        for (int c = 0; c < 4; ++c) {
            float v = acc[z][c];
            v += __shfl_xor(v, 16);
            v += __shfl_xor(v, 32);
            acc[z][c] = v;
        }
    }
    if (rsub == 0) {
        #pragma unroll
        for (int z = 0; z < 4; ++z) {
            #pragma unroll
            for (int c = 0; c < 4; ++c)
                red[wave][z * 64 + og * 4 + c] = acc[z][c];
        }
    }
    __syncthreads();
    // (z*64 + o) = t
    float s = red[0][t] + red[1][t] + red[2][t] + red[3][t];

    // ---- deterministic fixed-point accumulate (no fences) ----
    long long q = (long long)llrintf(s * FPSCALE);
    atomicAdd(&hacc[a * 256 + t], (u64)q);
    __syncthreads();                      // all 256 atomics performed (vmcnt)
    if (t == 0) s_ticket = atomicAdd(&done[a], 1u);
    __syncthreads();
    if (s_ticket != BPA - 1) return;      // not the last block for this 'a'

    // ---- finisher for this 'a': coherence-point reads via atomic RMW ----
    u64 raw = atomicAdd(&hacc[a * 256 + t], 0ULL);
    float h = (float)(long long)raw * (1.0f / FPSCALE);
    int o = t & 63;                       // t = z*64+o, wave == z
    float v = h * (1.0f / (1.0f + expf(-h))) * w_fc[o];  // silu * weight
    #pragma unroll
    for (int off = 32; off >= 1; off >>= 1) v += __shfl_xor(v, off);
    if (o == 0) out[wave * 16 + a] = v + b_fc[0];
}

extern "C" void kernel_launch(void* const* d_in, const int* in_sizes, int n_in,
                              void* d_out, int out_size, void* d_ws, size_t ws_size,
                              hipStream_t stream) {
    const float* x    = (const float*)d_in[0];
    const float* W    = (const float*)d_in[1];
    const float* w_fc = (const float*)d_in[2];
    const float* b_fc = (const float*)d_in[3];
    float* out = (float*)d_out;

    u64* hacc = (u64*)d_ws;                          // 4096 u64 = 32768 B
    u32* done = (u32*)((char*)d_ws + 32768);         // 16 u32

    (void)hipMemsetAsync(d_ws, 0, 32768 + 64, stream);
    k_main<<<16 * BPA, 256, 0, stream>>>((const f32x4*)W, x, w_fc, b_fc,
                                         hacc, done, out);
}

// Round 21
// 25.685 us; speedup vs baseline: 1.5288x; 1.5288x over previous
//
#include <hip/hip_runtime.h>
#include <math.h>

// B=4, N=16, K=16, H=64, O=1.  W: (a,b,d,e,k,o) fp32 = 256 MiB.
// h[z,a,o] = sum_j P[z,a,j] W[a,j,o];  P = <basis(a,b,k),basis(d,e,k)>_z
// out[z,a] = silu(h[z,a,:]) . w_fc + b_fc
//
// Cosine cutoff (dist>=5) + zero diagonal kill ~73% of W rows exactly ->
// their loads are skipped (bit-exact, ballot-derived wave-uniform mask).
// R21 = R17 structure (best, 28.2us) with COARSER BLOCKS: 1024 rows/block
// (1 b, 4 d, 16 e, 16 k), 1024 blocks total. Halves per-block fixed cost
// (prologue chain, epilogue reduce, part write) and part traffic; still
// 4 blocks/CU (16 waves/CU). 2-kernel split (fusion attempts R16/R20
// both regressed badly).
//
// ws (floats): part : [16][64][256] = 262,144 f @ 0   (1 MB)

#define NJ 65536
#define BPA 64    // blocks per 'a' -> 1024 blocks, 1024 rows each

typedef float f32x4 __attribute__((ext_vector_type(4)));
typedef unsigned int u32;

static constexpr double D_START = 0.006737946999085467; // exp(-5)

#define ACC8(pA, pB, wA, wB) do {                                              \
    acc[0][0] += pA.x * wA.x + pB.x * wB.x; acc[0][1] += pA.x * wA.y + pB.x * wB.y; \
    acc[0][2] += pA.x * wA.z + pB.x * wB.z; acc[0][3] += pA.x * wA.w + pB.x * wB.w; \
    acc[1][0] += pA.y * wA.x + pB.y * wB.x; acc[1][1] += pA.y * wA.y + pB.y * wB.y; \
    acc[1][2] += pA.y * wA.z + pB.y * wB.z; acc[1][3] += pA.y * wA.w + pB.y * wB.w; \
    acc[2][0] += pA.z * wA.x + pB.z * wB.x; acc[2][1] += pA.z * wA.y + pB.z * wB.y; \
    acc[2][2] += pA.z * wA.z + pB.z * wB.z; acc[2][3] += pA.z * wA.w + pB.z * wB.w; \
    acc[3][0] += pA.w * wA.x + pB.w * wB.x; acc[3][1] += pA.w * wA.y + pB.w * wB.y; \
    acc[3][2] += pA.w * wA.z + pB.w * wB.z; acc[3][3] += pA.w * wA.w + pB.w * wB.w; \
} while (0)

// basis vector (smear_k * diff / nsq) for pair (p,q) in batch z, rbf k.
__device__ __forceinline__ bool pair_basis(const float* __restrict__ x,
                                           int z, int p, int q, int k,
                                           float& bx, float& by, float& bz) {
    const float* xp = x + (z * 16 + p) * 3;
    const float* xq = x + (z * 16 + q) * 3;
    float d0 = xp[0] - xq[0], d1 = xp[1] - xq[1], d2 = xp[2] - xq[2];
    float nsq = d0 * d0 + d1 * d1 + d2 * d2 + 1e-5f;
    float nrm = sqrtf(nsq);
    if (nrm >= 5.0f) return false;                 // cut == 0 -> basis == 0
    float cut = 0.5f * (cosf(nrm * 0.6283185307179586f) + 1.0f);
    float ex = expf(-nrm); // alpha=1, CUT_LO=0
    const float START = (float)D_START;
    const float STEP  = (float)((1.0 - D_START) / 15.0);
    const float BETA  = (float)(1.0 / ((0.125 * (1.0 - D_START)) * (0.125 * (1.0 - D_START))));
    float m = START + STEP * (float)k;
    float dmm = ex - m;
    float s = cut * expf(-BETA * dmm * dmm) / nsq; // fold /nsq of diff into smear
    bx = s * d0; by = s * d1; bz = s * d2;
    return true;
}

__global__ __launch_bounds__(256) void k_main(const f32x4* __restrict__ W4,
                                              const float* __restrict__ x,
                                              float* __restrict__ part) {
    int a   = blockIdx.x >> 6;        // sequential mapping (best measured)
    int blk = blockIdx.x & (BPA - 1); // (b, d-quad)

    __shared__ f32x4 p_lds[1024];
    __shared__ float red[4][256];

    // ---- prologue: P for this block's 1024 j-rows (j = blk*1024 + rloc) ----
    // thread t covers rows t+256*h for d = dq+h, h=0..3
    int t = threadIdx.x;
    f32x4 p0 = {0.f,0.f,0.f,0.f}, p1 = {0.f,0.f,0.f,0.f};
    f32x4 p2 = {0.f,0.f,0.f,0.f}, p3 = {0.f,0.f,0.f,0.f};
    {
        int e = t >> 4, k = t & 15;
        int b = blk >> 2, dq = (blk & 3) * 4;
        #pragma unroll
        for (int z = 0; z < 4; ++z) {
            float ux, uy, uz;
            if (pair_basis(x, z, a, b, k, ux, uy, uz)) { // block-uniform branch
                float vx, vy, vz;
                if (pair_basis(x, z, dq + 0, e, k, vx, vy, vz))
                    p0[z] = ux * vx + uy * vy + uz * vz;
                if (pair_basis(x, z, dq + 1, e, k, vx, vy, vz))
                    p1[z] = ux * vx + uy * vy + uz * vz;
                if (pair_basis(x, z, dq + 2, e, k, vx, vy, vz))
                    p2[z] = ux * vx + uy * vy + uz * vz;
                if (pair_basis(x, z, dq + 3, e, k, vx, vy, vz))
                    p3[z] = ux * vx + uy * vy + uz * vz;
            }
        }
    }
    bool f0 = (fabsf(p0.x) + fabsf(p0.y) + fabsf(p0.z) + fabsf(p0.w)) != 0.0f;
    bool f1 = (fabsf(p1.x) + fabsf(p1.y) + fabsf(p1.z) + fabsf(p1.w)) != 0.0f;
    bool f2 = (fabsf(p2.x) + fabsf(p2.y) + fabsf(p2.z) + fabsf(p2.w)) != 0.0f;
    bool f3 = (fabsf(p3.x) + fabsf(p3.y) + fabsf(p3.z) + fabsf(p3.w)) != 0.0f;
    unsigned long long bal0 = __ballot(f0);  // rows [0*256 + w*64, +64)
    unsigned long long bal1 = __ballot(f1);  // rows [1*256 + ...]
    unsigned long long bal2 = __ballot(f2);
    unsigned long long bal3 = __ballot(f3);
    p_lds[t]       = p0;
    p_lds[t + 256] = p1;
    p_lds[t + 512] = p2;
    p_lds[t + 768] = p3;
    __syncthreads();

    int wave = t >> 6;
    int lane = t & 63;
    int og   = lane & 15;  // group of 4 'o' columns
    int rsub = lane >> 4;  // row within the 4-row group

    // 32-bit group mask: bits [8h..8h+7] = groups of quarter h
    u32 mask = 0;
    #pragma unroll
    for (int g = 0; g < 8; ++g) {
        if ((bal0 >> (8 * g)) & 0xFFull) mask |= 1u << g;
        if ((bal1 >> (8 * g)) & 0xFFull) mask |= 1u << (g + 8);
        if ((bal2 >> (8 * g)) & 0xFFull) mask |= 1u << (g + 16);
        if ((bal3 >> (8 * g)) & 0xFFull) mask |= 1u << (g + 24);
    }

    float acc[4][4] = {{0.f, 0.f, 0.f, 0.f}, {0.f, 0.f, 0.f, 0.f},
                       {0.f, 0.f, 0.f, 0.f}, {0.f, 0.f, 0.f, 0.f}};
    size_t rowbase = (size_t)a * NJ + (size_t)blk * 1024;
    // ---- 2-group-per-iter pipelined skip loop (4 KB in flight) ----
    while (mask) {  // wave-uniform: mask derived from ballots
        int g1 = (int)__builtin_ctz(mask);
        mask &= mask - 1;
        int rloc1 = (g1 >> 3) * 256 + wave * 64 + (g1 & 7) * 8 + rsub;
        f32x4 pA1 = p_lds[rloc1];
        f32x4 pB1 = p_lds[rloc1 + 4];
        f32x4 wA1 = W4[(rowbase + rloc1) * 16 + og];
        f32x4 wB1 = W4[(rowbase + rloc1 + 4) * 16 + og];
        if (mask) {
            int g2 = (int)__builtin_ctz(mask);
            mask &= mask - 1;
            int rloc2 = (g2 >> 3) * 256 + wave * 64 + (g2 & 7) * 8 + rsub;
            f32x4 pA2 = p_lds[rloc2];
            f32x4 pB2 = p_lds[rloc2 + 4];
            f32x4 wA2 = W4[(rowbase + rloc2) * 16 + og];   // in flight
            f32x4 wB2 = W4[(rowbase + rloc2 + 4) * 16 + og];
            ACC8(pA1, pB1, wA1, wB1);                      // waits vmcnt(2)
            ACC8(pA2, pB2, wA2, wB2);
        } else {
            ACC8(pA1, pB1, wA1, wB1);
        }
    }

    // reduce across the 4 row-subgroups (lane bits 4,5)
    #pragma unroll
    for (int z = 0; z < 4; ++z) {
        #pragma unroll
        for (int c = 0; c < 4; ++c) {
            float v = acc[z][c];
            v += __shfl_xor(v, 16);
            v += __shfl_xor(v, 32);
            acc[z][c] = v;
        }
    }
    if (rsub == 0) {
        #pragma unroll
        for (int z = 0; z < 4; ++z) {
            #pragma unroll
            for (int c = 0; c < 4; ++c)
                red[wave][z * 64 + og * 4 + c] = acc[z][c];
        }
    }
    __syncthreads();
    // (z*64 + o) = t
    float s = red[0][t] + red[1][t] + red[2][t] + red[3][t];
    part[((size_t)a * BPA + blk) * 256 + t] = s;
}

__global__ void k_out(const float* __restrict__ part, const float* __restrict__ w_fc,
                      const float* __restrict__ b_fc, float* __restrict__ out) {
    // one block per (z,a); 256 threads = 4 blk-quarters x 64 'o'
    int z = blockIdx.x >> 4, a = blockIdx.x & 15;
    int o = threadIdx.x & 63, bq = threadIdx.x >> 6;
    float s = 0.f;
    for (int blk = bq; blk < BPA; blk += 4)
        s += part[((size_t)a * BPA + blk) * 256 + z * 64 + o]; // coalesced over o
    __shared__ float red[4][64];
    red[bq][o] = s;
    __syncthreads();
    if (threadIdx.x < 64) {
        float h = red[0][o] + red[1][o] + red[2][o] + red[3][o];
        float v = h * (1.0f / (1.0f + expf(-h))) * w_fc[o]; // silu * weight
        #pragma unroll
        for (int off = 32; off >= 1; off >>= 1) v += __shfl_xor(v, off);
        if (o == 0) out[z * 16 + a] = v + b_fc[0];
    }
}

extern "C" void kernel_launch(void* const* d_in, const int* in_sizes, int n_in,
                              void* d_out, int out_size, void* d_ws, size_t ws_size,
                              hipStream_t stream) {
    const float* x    = (const float*)d_in[0];
    const float* W    = (const float*)d_in[1];
    const float* w_fc = (const float*)d_in[2];
    const float* b_fc = (const float*)d_in[3];
    float* ws  = (float*)d_ws;
    float* out = (float*)d_out;

    float* part = ws;                 // 262,144 floats

    k_main<<<16 * BPA, 256, 0, stream>>>((const f32x4*)W, x, part);
    k_out<<<64, 256, 0, stream>>>(part, w_fc, b_fc, out);
}